// Round 7
// baseline (336.499 us; speedup 1.0000x reference)
//
#include <hip/hip_runtime.h>
#include <hip/hip_bf16.h>

#define BB 2
#define SS 2048
#define DD 1024
#define HH 16
#define RR 64
#define DH 64
#define BH (BB*HH)      // 32
#define MM (BB*SS)      // 4096
#define CH 32
#define NCH (SS/CH)     // 64
#define CSROW (RR*DH + RR)  // 4160

using short8 = __attribute__((ext_vector_type(8))) short;
using f32x4  = __attribute__((ext_vector_type(4))) float;

typedef const __attribute__((address_space(1))) unsigned int* gp_t;
typedef __attribute__((address_space(3))) unsigned int* lp_t;

__device__ __forceinline__ void gll16(const void* g, void* l) {
    __builtin_amdgcn_global_load_lds((gp_t)g, (lp_t)l, 16, 0, 0);
}

__device__ __forceinline__ unsigned short f2bf(float x) {
    __hip_bfloat16 h = __float2bfloat16(x);
    return *(unsigned short*)&h;
}

__device__ __forceinline__ float bf2f(unsigned short u) {
    return __uint_as_float(((unsigned int)u) << 16);
}

__device__ __forceinline__ short8 pk8(f32x4 lo, f32x4 hi) {
    short8 r;
    r[0] = (short)f2bf(lo[0]); r[1] = (short)f2bf(lo[1]);
    r[2] = (short)f2bf(lo[2]); r[3] = (short)f2bf(lo[3]);
    r[4] = (short)f2bf(hi[0]); r[5] = (short)f2bf(hi[1]);
    r[6] = (short)f2bf(hi[2]); r[7] = (short)f2bf(hi[3]);
    return r;
}

// ---------------- pre: weight transposes + biases + wg (qkv conversion now fused into GEMM1) ----------------
__global__ __launch_bounds__(256) void k_pre(
    const float* __restrict__ bq, const float* __restrict__ bk, const float* __restrict__ bv,
    const float* __restrict__ wq, const float* __restrict__ wk,
    const float* __restrict__ wv, const float* __restrict__ wc,
    const float* __restrict__ wg,
    float* __restrict__ biasb,
    __hip_bfloat16* __restrict__ WT, __hip_bfloat16* __restrict__ wcT,
    short* __restrict__ wgbT)
{
    int bid = blockIdx.x;
    __shared__ float tile[64][65];
    if (bid < 1024) {
        int zz = bid >> 8;
        int sub = bid & 255;
        if (sub == 0 && zz < 3) {
            const float* bb = (zz == 0) ? bq : (zz == 1) ? bk : bv;
            for (int t = threadIdx.x; t < 1024; t += 256)
                biasb[zz * 1024 + t] = bb[t];
        }
        const float* W = (zz == 0) ? wq : (zz == 1) ? wk : (zz == 2) ? wv : wc;
        __hip_bfloat16* T = (zz < 3) ? (WT + (size_t)zz * 1048576) : wcT;
        int k0 = (sub >> 4) * 64, n0 = (sub & 15) * 64;
        for (int i = threadIdx.x; i < 4096; i += 256) {
            int r = i >> 6, cc = i & 63;
            tile[r][cc] = W[(size_t)(k0 + r) * 1024 + n0 + cc];
        }
        __syncthreads();
        for (int i = threadIdx.x; i < 4096; i += 256) {
            int nl = i >> 6, kl = i & 63;
            T[(size_t)(n0 + nl) * 1024 + k0 + kl] = __float2bfloat16(tile[kl][nl]);
        }
    } else {
        int hx = bid - 1024;
        for (int i = threadIdx.x; i < 4096; i += 256)
            tile[i >> 6][i & 63] = wg[(size_t)hx * 4096 + i];   // tile[d][r]
        __syncthreads();
        for (int i = threadIdx.x; i < 4096; i += 256) {
            int r = i >> 6, d = i & 63;
            wgbT[(size_t)hx * 4096 + r * 64 + d] = (short)f2bf(tile[d][r]);
        }
    }
}

// ---------------- GEMM, BK=64, XCD-swizzled ----------------
// AF32=true:  A read directly from f32 (q/k/v), converted in-flight, reg-staged to LDS.
// AF32=false: A read from bf16 (attnb) via global_load_lds.
// mode==1: z<2 -> fused phi epilogue (bf16); z==2 -> bf16 vh write. mode==0: plain f32 C.
template<bool AF32>
__global__ __launch_bounds__(256) void gemm_bt(
    const float* __restrict__ Aq, const float* __restrict__ Ak, const float* __restrict__ Av,
    const __hip_bfloat16* __restrict__ Xb,
    const __hip_bfloat16* __restrict__ WT,
    const float* __restrict__ bias, float* __restrict__ Cout,
    const short* __restrict__ wgbT,
    unsigned short* __restrict__ qp_out, unsigned short* __restrict__ kp_out2,
    long zsW, long zsB, long zsC, int mode)
{
    const int K = 1024, N = 1024;
    int z = blockIdx.z;
    const short* Wz = (const short*)(WT + (size_t)z * zsW);
    const float* bz = bias + (size_t)z * zsB;
    float* Cz = Cout + (size_t)z * zsC;

    // XCD-aware bijective swizzle (256 blocks per z-slice, 256 % 8 == 0)
    int bid = blockIdx.y * gridDim.x + blockIdx.x;
    int nb_cnt = gridDim.x * gridDim.y;
    int cpx = nb_cnt >> 3;
    int swz = (bid & 7) * cpx + (bid >> 3);
    int nb = swz % gridDim.x;
    int mb = swz / gridDim.x;
    int m0 = mb * 128;
    int n0 = nb * 128;

    // LDS union: main loop As/Bs = 32KB; epilogue wgT+xw = 36KB
    __shared__ short smem[18432];
    short* As = smem;            // [kk][128][32]
    short* Bs = smem + 8192;
    short* wgT = smem;           // [2][64][72]
    short* xw  = smem + 9216;    // [4 waves][32][72]

    int tid = threadIdx.x;
    int lane = tid & 63;
    int w = tid >> 6;
    int wm = (w >> 1) * 64, wn = (w & 1) * 64;

    f32x4 acc[4][4] = {};

    int srow = tid >> 2;
    int scol = (tid & 3) * 8;
    const short* Bg = Wz + (size_t)(n0 + srow) * K + scol;

    // A sources
    const float* Az = (z == 0) ? Aq : (z == 1) ? Ak : Av;
    const float* Ar0 = Az + (size_t)(m0 + srow) * K + scol;
    const float* Ar1 = Ar0 + (size_t)64 * K;
    const short* Ag = (const short*)Xb + (size_t)(m0 + srow) * K + scol;

    int fr = lane & 15, kg = (lane >> 4) * 8;

    f32x4 ar[8];
    if (AF32) {
        ar[0] = *(const f32x4*)(Ar0);      ar[1] = *(const f32x4*)(Ar0 + 4);
        ar[2] = *(const f32x4*)(Ar1);      ar[3] = *(const f32x4*)(Ar1 + 4);
        ar[4] = *(const f32x4*)(Ar0 + 32); ar[5] = *(const f32x4*)(Ar0 + 36);
        ar[6] = *(const f32x4*)(Ar1 + 32); ar[7] = *(const f32x4*)(Ar1 + 36);
    }

    for (int kt = 0; kt < K / 64; ++kt) {
        const short* Bk = Bg + kt * 64;
        __syncthreads();
        if (AF32) {
            *(short8*)(As + tid * 8)        = pk8(ar[0], ar[1]);
            *(short8*)(As + 2048 + tid * 8) = pk8(ar[2], ar[3]);
            *(short8*)(As + 4096 + tid * 8) = pk8(ar[4], ar[5]);
            *(short8*)(As + 6144 + tid * 8) = pk8(ar[6], ar[7]);
        } else {
            const short* Ak_ = Ag + kt * 64;
            gll16(Ak_,                       As + tid * 8);
            gll16(Ak_ + (size_t)64 * K,      As + 2048 + tid * 8);
            gll16(Ak_ + 32,                  As + 4096 + tid * 8);
            gll16(Ak_ + 32 + (size_t)64 * K, As + 6144 + tid * 8);
        }
        gll16(Bk,                       Bs + tid * 8);
        gll16(Bk + (size_t)64 * K,      Bs + 2048 + tid * 8);
        gll16(Bk + 32,                  Bs + 4096 + tid * 8);
        gll16(Bk + 32 + (size_t)64 * K, Bs + 6144 + tid * 8);
        if (AF32 && kt + 1 < K / 64) {
            int c0 = (kt + 1) * 64;
            ar[0] = *(const f32x4*)(Ar0 + c0);      ar[1] = *(const f32x4*)(Ar0 + c0 + 4);
            ar[2] = *(const f32x4*)(Ar1 + c0);      ar[3] = *(const f32x4*)(Ar1 + c0 + 4);
            ar[4] = *(const f32x4*)(Ar0 + c0 + 32); ar[5] = *(const f32x4*)(Ar0 + c0 + 36);
            ar[6] = *(const f32x4*)(Ar1 + c0 + 32); ar[7] = *(const f32x4*)(Ar1 + c0 + 36);
        }
        __syncthreads();

#pragma unroll
        for (int kk = 0; kk < 2; ++kk) {
            short8 af[4], bf[4];
#pragma unroll
            for (int mi = 0; mi < 4; ++mi)
                af[mi] = *(const short8*)&As[kk * 4096 + (wm + mi * 16 + fr) * 32 + kg];
#pragma unroll
            for (int ni = 0; ni < 4; ++ni)
                bf[ni] = *(const short8*)&Bs[kk * 4096 + (wn + ni * 16 + fr) * 32 + kg];
#pragma unroll
            for (int mi = 0; mi < 4; ++mi)
#pragma unroll
                for (int ni = 0; ni < 4; ++ni)
                    acc[mi][ni] = __builtin_amdgcn_mfma_f32_16x16x32_bf16(af[mi], bf[ni], acc[mi][ni], 0, 0, 0);
        }
    }

    int g = lane >> 4, c4 = lane & 15;

    if (mode == 1 && z < 2) {
        // -------- fused phi epilogue (bf16 output) --------
        const float nd = 0.35355339059327373f;  // 64^-0.25
        unsigned short* O = (z == 0) ? qp_out : kp_out2;
        int h = nb * 2 + (w & 1);
        int b = m0 >> 11;
        float bias_n[4];
#pragma unroll
        for (int ni = 0; ni < 4; ++ni) bias_n[ni] = bz[n0 + wn + ni * 16 + c4];

        __syncthreads();
        {
            int row = tid >> 2, part = tid & 3;
#pragma unroll
            for (int hl = 0; hl < 2; ++hl) {
                const short* src = wgbT + ((size_t)(nb * 2 + hl)) * 4096 + row * 64 + part * 16;
                short8 v0 = *(const short8*)src;
                short8 v1 = *(const short8*)(src + 8);
                *(short8*)&wgT[hl * 4608 + row * 72 + part * 16] = v0;
                *(short8*)&wgT[hl * 4608 + row * 72 + part * 16 + 8] = v1;
            }
        }
        __syncthreads();

        short* xww = xw + w * 2304;
        const short* wgh = wgT + (w & 1) * 4608;

#pragma unroll
        for (int pass = 0; pass < 2; ++pass) {
            float nrm[2][4];
#pragma unroll
            for (int mi_l = 0; mi_l < 2; ++mi_l) {
                int mi = pass * 2 + mi_l;
                float part_n[4] = {0.f, 0.f, 0.f, 0.f};
#pragma unroll
                for (int ni = 0; ni < 4; ++ni)
#pragma unroll
                    for (int i = 0; i < 4; ++i) {
                        float xv = (acc[mi][ni][i] + bias_n[ni]) * nd;
                        part_n[i] += xv * xv;
                        xww[(mi_l * 16 + g * 4 + i) * 72 + ni * 16 + c4] = (short)f2bf(xv);
                    }
#pragma unroll
                for (int i = 0; i < 4; ++i) {
                    float t = part_n[i];
                    t += __shfl_xor(t, 1, 64);
                    t += __shfl_xor(t, 2, 64);
                    t += __shfl_xor(t, 4, 64);
                    t += __shfl_xor(t, 8, 64);
                    nrm[mi_l][i] = t;
                }
            }
            short8 afr[2][2], bfr[4][2];
#pragma unroll
            for (int mi_l = 0; mi_l < 2; ++mi_l)
#pragma unroll
                for (int kk = 0; kk < 2; ++kk)
                    afr[mi_l][kk] = *(const short8*)&xww[(mi_l * 16 + c4) * 72 + kk * 32 + g * 8];
#pragma unroll
            for (int ri = 0; ri < 4; ++ri)
#pragma unroll
                for (int kk = 0; kk < 2; ++kk)
                    bfr[ri][kk] = *(const short8*)&wgh[(ri * 16 + c4) * 72 + kk * 32 + g * 8];
            f32x4 p[2][4] = {};
#pragma unroll
            for (int mi_l = 0; mi_l < 2; ++mi_l)
#pragma unroll
                for (int ri = 0; ri < 4; ++ri)
#pragma unroll
                    for (int kk = 0; kk < 2; ++kk)
                        p[mi_l][ri] = __builtin_amdgcn_mfma_f32_16x16x32_bf16(afr[mi_l][kk], bfr[ri][kk], p[mi_l][ri], 0, 0, 0);
#pragma unroll
            for (int mi_l = 0; mi_l < 2; ++mi_l)
#pragma unroll
                for (int ri = 0; ri < 4; ++ri)
#pragma unroll
                    for (int i = 0; i < 4; ++i) {
                        int mi = pass * 2 + mi_l;
                        float val = 0.125f * __expf(p[mi_l][ri][i] - 0.5f * nrm[mi_l][i]);
                        int row = m0 + wm + mi * 16 + g * 4 + i;
                        int s = row & 2047;
                        O[((size_t)(b * 16 + h) * SS + s) * RR + ri * 16 + c4] = f2bf(val);
                    }
        }
        return;
    }

    int rg = g * 4;
    if (mode == 1) {
        // -------- vh epilogue: bf16 --------
        unsigned short* Cz16 = (unsigned short*)Cz;
#pragma unroll
        for (int mi = 0; mi < 4; ++mi)
#pragma unroll
            for (int ni = 0; ni < 4; ++ni) {
                int gn = n0 + wn + ni * 16 + fr;
                float bval = bz[gn];
#pragma unroll
                for (int i = 0; i < 4; ++i) {
                    int gm = m0 + wm + mi * 16 + rg + i;
                    Cz16[(size_t)gm * N + gn] = f2bf(acc[mi][ni][i] + bval);
                }
            }
        return;
    }

    // -------- plain f32 epilogue (final output GEMM) --------
#pragma unroll
    for (int mi = 0; mi < 4; ++mi)
#pragma unroll
        for (int ni = 0; ni < 4; ++ni) {
            int gn = n0 + wn + ni * 16 + fr;
            float bval = bz[gn];
#pragma unroll
            for (int i = 0; i < 4; ++i) {
                int gm = m0 + wm + mi * 16 + rg + i;
                Cz[(size_t)gm * N + gn] = acc[mi][ni][i] + bval;
            }
        }
}

// ---------------- chunk sums (bf16 inputs staged to f32 LDS) ----------------
__global__ __launch_bounds__(64) void k_chunksum(
    const unsigned short* __restrict__ kprime, const unsigned short* __restrict__ vh,
    float* __restrict__ cs)
{
    int c = blockIdx.x;
    int bh = blockIdx.y;
    int b = bh >> 4, h = bh & 15;
    int lane = threadIdx.x;
    __shared__ float kp[CH][RR];
    __shared__ float vv[CH][RR];
    size_t rowbase = (size_t)bh * SS + c * CH;
    const unsigned short* kpb = kprime + rowbase * RR;
    const unsigned short* vb = vh + ((size_t)b * SS + c * CH) * DD + h * DH;
#pragma unroll
    for (int i = 0; i < 4; ++i) {
        int flat = i * 64 + lane;          // 256 granules of 8 bf16
        int row = flat >> 3, c8 = (flat & 7) * 8;
        short8 k8 = *(const short8*)(kpb + (size_t)row * RR + c8);
        short8 v8 = *(const short8*)(vb + (size_t)row * DD + c8);
#pragma unroll
        for (int e = 0; e < 8; ++e) {
            kp[row][c8 + e] = bf2f((unsigned short)k8[e]);
            vv[row][c8 + e] = bf2f((unsigned short)v8[e]);
        }
    }
    __syncthreads();

    float st[RR];
#pragma unroll
    for (int r = 0; r < RR; ++r) st[r] = 0.f;
    float kpsum = 0.f;
    for (int s = 0; s < CH; ++s) {
        float vd = vv[s][lane];
        kpsum += kp[s][lane];
#pragma unroll
        for (int rq = 0; rq < RR / 4; ++rq) {
            f32x4 kq = *(const f32x4*)&kp[s][rq * 4];
            st[rq * 4 + 0] += kq[0] * vd;
            st[rq * 4 + 1] += kq[1] * vd;
            st[rq * 4 + 2] += kq[2] * vd;
            st[rq * 4 + 3] += kq[3] * vd;
        }
    }
    float* out = cs + (size_t)(bh * NCH + c) * CSROW;
#pragma unroll
    for (int r = 0; r < RR; ++r) out[r * 64 + lane] = st[r];
    out[4096 + lane] = kpsum;
}

// ---------------- exclusive scan over chunks ----------------
__global__ __launch_bounds__(256) void k_scan(float* __restrict__ cs)
{
    int t = blockIdx.x * 256 + threadIdx.x;
    if (t >= BH * CSROW) return;
    int bh = t / CSROW;
    int e = t - bh * CSROW;
    float* p = cs + (size_t)bh * NCH * CSROW + e;
    float v[NCH];
#pragma unroll
    for (int c = 0; c < NCH; ++c) v[c] = p[(size_t)c * CSROW];
    float run = 0.f;
#pragma unroll
    for (int c = 0; c < NCH; ++c) {
        float x = v[c];
        p[(size_t)c * CSROW] = run;
        run += x;
    }
}

// ---------------- final: bf16 inputs staged; s-loop is a near-pure write stream ----------------
__global__ __launch_bounds__(64) void k_scanfinal(
    const unsigned short* __restrict__ kprime, const unsigned short* __restrict__ qprime,
    const unsigned short* __restrict__ vh, const float* __restrict__ cs,
    float* __restrict__ kp_out, float* __restrict__ kv_out,
    __hip_bfloat16* __restrict__ attnb)
{
    int c = blockIdx.x;
    int bh = blockIdx.y;
    int b = bh >> 4, h = bh & 15;
    int lane = threadIdx.x;
    int g = lane >> 4, c4 = lane & 15;
    __shared__ float kp[CH][RR];
    __shared__ float qp[CH][RR];
    __shared__ float vv[CH][RR];
    size_t rowbase = (size_t)bh * SS + c * CH;
    const unsigned short* kpb = kprime + rowbase * RR;
    const unsigned short* qpb = qprime + rowbase * RR;
    const unsigned short* vb = vh + ((size_t)b * SS + c * CH) * DD + h * DH;
#pragma unroll
    for (int i = 0; i < 4; ++i) {
        int flat = i * 64 + lane;
        int row = flat >> 3, c8 = (flat & 7) * 8;
        short8 k8 = *(const short8*)(kpb + (size_t)row * RR + c8);
        short8 q8 = *(const short8*)(qpb + (size_t)row * RR + c8);
        short8 v8 = *(const short8*)(vb + (size_t)row * DD + c8);
#pragma unroll
        for (int e = 0; e < 8; ++e) {
            kp[row][c8 + e] = bf2f((unsigned short)k8[e]);
            qp[row][c8 + e] = bf2f((unsigned short)q8[e]);
            vv[row][c8 + e] = bf2f((unsigned short)v8[e]);
        }
    }

    const float* off = cs + (size_t)(bh * NCH + c) * CSROW;
    f32x4 st[16];
#pragma unroll
    for (int j = 0; j < 16; ++j)
        st[j] = *(const f32x4*)&off[(4 * j + g) * 64 + 4 * c4];
    float kps = off[4096 + lane];
    __syncthreads();

    for (int s = 0; s < CH; ++s) {
        float kpl = kp[s][lane];
        kps += kpl;
        size_t srow = rowbase + s;
        kp_out[srow * RR + lane] = kps;

        float qksum = qp[s][lane] * kps;
#pragma unroll
        for (int m = 1; m < 64; m <<= 1) qksum += __shfl_xor(qksum, m, 64);

        f32x4 v4 = *(const f32x4*)&vv[s][4 * c4];
        f32x4 accp = {0.f, 0.f, 0.f, 0.f};
        float* kvp = kv_out + srow * (size_t)(RR * DH);
#pragma unroll
        for (int j = 0; j < 16; ++j) {
            float kpj = kp[s][4 * j + g];
            float qpj = qp[s][4 * j + g];
            st[j] += kpj * v4;
            __builtin_nontemporal_store(st[j], (f32x4*)(kvp + (4 * j + g) * 64 + 4 * c4));
            accp += qpj * st[j];
        }
#pragma unroll
        for (int e = 0; e < 4; ++e) {
            accp[e] += __shfl_xor(accp[e], 16, 64);
            accp[e] += __shfl_xor(accp[e], 32, 64);
        }
        float rs = 1.0f / (1e-6f + qksum);
        if (g == 0) {
            ushort4 pkt;
            pkt.x = f2bf(accp[0] * rs);
            pkt.y = f2bf(accp[1] * rs);
            pkt.z = f2bf(accp[2] * rs);
            pkt.w = f2bf(accp[3] * rs);
            *(ushort4*)((unsigned short*)attnb + ((size_t)b * SS + c * CH + s) * DD + h * DH + 4 * c4) = pkt;
        }
    }
}

extern "C" void kernel_launch(void* const* d_in, const int* in_sizes, int n_in,
                              void* d_out, int out_size, void* d_ws, size_t ws_size,
                              hipStream_t stream) {
    const float* v_in  = (const float*)d_in[0];
    const float* k_in  = (const float*)d_in[1];
    const float* q_in  = (const float*)d_in[2];
    const float* wq_w  = (const float*)d_in[3];
    const float* wq_b  = (const float*)d_in[4];
    const float* wk_w  = (const float*)d_in[5];
    const float* wk_b  = (const float*)d_in[6];
    const float* wv_w  = (const float*)d_in[7];
    const float* wv_b  = (const float*)d_in[8];
    const float* wc_w  = (const float*)d_in[9];
    const float* wc_b  = (const float*)d_in[10];
    const float* wg    = (const float*)d_in[11];

    char* ws = (char*)d_ws;
    __hip_bfloat16* WT    = (__hip_bfloat16*)(ws + 25165824);   // [3][1024][1024] bf16
    __hip_bfloat16* wcT   = (__hip_bfloat16*)(ws + 31457280);   // [1024][1024] bf16
    float* biasb          = (float*)(ws + 33554432);            // [3][1024]
    float* qhkv           = (float*)(ws + 33570816);            // f32 slots (z=2 holds bf16 vh)
    unsigned short* qprime = (unsigned short*)(ws + 83902464);  // [32][2048][64] bf16
    unsigned short* kprime = (unsigned short*)(ws + 100679680); // [32][2048][64] bf16
    float* cs             = (float*)(ws + 117456896);           // [32][64][4160] f32
    __hip_bfloat16* attnb = (__hip_bfloat16*)(ws + 151535616);  // [4096][1024] bf16
    short* wgbT           = (short*)(ws + 159924224);           // [16][64][64] bf16

    float* kp_out = (float*)d_out;                 // [32][2048][64]
    float* kv_out = kp_out + 4194304;              // [32][2048][64][64]
    float* out_o  = kv_out + 268435456;            // [4096][1024]
    unsigned short* vh16 = (unsigned short*)(qhkv + 2 * 4194304);

    k_pre<<<dim3(1040), 256, 0, stream>>>(wq_b, wk_b, wv_b,
                                          wq_w, wk_w, wv_w, wc_w, wg,
                                          biasb, WT, wcT, wgbT);
    gemm_bt<true><<<dim3(8, 32, 3), 256, 0, stream>>>(
        q_in, k_in, v_in, nullptr, WT, biasb, qhkv, wgbT, qprime, kprime,
        1048576L, 1024L, 4194304L, 1);
    k_chunksum<<<dim3(NCH, BH), 64, 0, stream>>>(kprime, vh16, cs);
    k_scan<<<dim3(520), 256, 0, stream>>>(cs);
    k_scanfinal<<<dim3(NCH, BH), 64, 0, stream>>>(kprime, qprime, vh16, cs,
                                                  kp_out, kv_out, attnb);
    gemm_bt<false><<<dim3(8, 32, 1), 256, 0, stream>>>(
        nullptr, nullptr, nullptr, attnb, wcT, wc_b, out_o, wgbT, qprime, kprime,
        0L, 0L, 0L, 0);
}

// Round 8
// 325.100 us; speedup vs baseline: 1.0351x; 1.0351x over previous
//
#include <hip/hip_runtime.h>
#include <hip/hip_bf16.h>

#define BB 2
#define SS 2048
#define DD 1024
#define HH 16
#define RR 64
#define DH 64
#define BH (BB*HH)      // 32
#define MM (BB*SS)      // 4096
#define CH 32
#define NCH (SS/CH)     // 64
#define CSROW (RR*DH + RR)  // 4160

using short8 = __attribute__((ext_vector_type(8))) short;
using f32x4  = __attribute__((ext_vector_type(4))) float;

typedef const __attribute__((address_space(1))) unsigned int* gp_t;
typedef __attribute__((address_space(3))) unsigned int* lp_t;

__device__ __forceinline__ void gll16(const void* g, void* l) {
    __builtin_amdgcn_global_load_lds((gp_t)g, (lp_t)l, 16, 0, 0);
}

__device__ __forceinline__ unsigned short f2bf(float x) {
    __hip_bfloat16 h = __float2bfloat16(x);
    return *(unsigned short*)&h;
}

__device__ __forceinline__ float bf2f(unsigned short u) {
    return __uint_as_float(((unsigned int)u) << 16);
}

// ---------------- fused pre (flattened 1D grid) ----------------
__global__ __launch_bounds__(256) void k_pre(
    const float* __restrict__ q, const float* __restrict__ k, const float* __restrict__ v,
    const float* __restrict__ bq, const float* __restrict__ bk, const float* __restrict__ bv,
    const float* __restrict__ wq, const float* __restrict__ wk,
    const float* __restrict__ wv, const float* __restrict__ wc,
    const float* __restrict__ wg,
    __hip_bfloat16* __restrict__ Xb, float* __restrict__ biasb,
    __hip_bfloat16* __restrict__ WT, __hip_bfloat16* __restrict__ wcT,
    short* __restrict__ wgbT)
{
    int bid = blockIdx.x;
    __shared__ float tile[64][65];
    if (bid < 12288) {
        int z = bid >> 12;
        int bx = bid & 4095;
        const float* src = (z == 0) ? q : (z == 1) ? k : v;
        size_t i = ((size_t)bx * 256 + threadIdx.x) * 4;
        float4 f = *(const float4*)(src + i);
        __hip_bfloat16* dst = Xb + (size_t)z * 4194304 + i;
        dst[0] = __float2bfloat16(f.x);
        dst[1] = __float2bfloat16(f.y);
        dst[2] = __float2bfloat16(f.z);
        dst[3] = __float2bfloat16(f.w);
        if (bx == 0) {
            const float* bb = (z == 0) ? bq : (z == 1) ? bk : bv;
            for (int t = threadIdx.x; t < 1024; t += 256)
                biasb[z * 1024 + t] = bb[t];
        }
    } else if (bid < 13312) {
        int sub = bid - 12288;
        int zz = sub >> 8;
        sub &= 255;
        const float* W = (zz == 0) ? wq : (zz == 1) ? wk : (zz == 2) ? wv : wc;
        __hip_bfloat16* T = (zz < 3) ? (WT + (size_t)zz * 1048576) : wcT;
        int k0 = (sub >> 4) * 64, n0 = (sub & 15) * 64;
        for (int i = threadIdx.x; i < 4096; i += 256) {
            int r = i >> 6, cc = i & 63;
            tile[r][cc] = W[(size_t)(k0 + r) * 1024 + n0 + cc];
        }
        __syncthreads();
        for (int i = threadIdx.x; i < 4096; i += 256) {
            int nl = i >> 6, kl = i & 63;
            T[(size_t)(n0 + nl) * 1024 + k0 + kl] = __float2bfloat16(tile[kl][nl]);
        }
    } else {
        int hx = bid - 13312;
        for (int i = threadIdx.x; i < 4096; i += 256)
            tile[i >> 6][i & 63] = wg[(size_t)hx * 4096 + i];   // tile[d][r]
        __syncthreads();
        for (int i = threadIdx.x; i < 4096; i += 256) {
            int r = i >> 6, d = i & 63;
            wgbT[(size_t)hx * 4096 + r * 64 + d] = (short)f2bf(tile[d][r]);
        }
    }
}

// ---------------- GEMM, BK=64 (two stacked 128x32 sub-tiles), XCD-swizzled ----------------
// mode==1: z<2 -> fused phi epilogue (bf16 out); z==2 -> bf16 vh write.
// mode==0: plain f32 epilogue.
__global__ __launch_bounds__(256) void gemm_bt(
    const __hip_bfloat16* __restrict__ X, const __hip_bfloat16* __restrict__ WT,
    const float* __restrict__ bias, float* __restrict__ Cout,
    const short* __restrict__ wgbT,
    unsigned short* __restrict__ qp_out, unsigned short* __restrict__ kp_out2,
    long zsX, long zsW, long zsB, long zsC, int mode)
{
    const int K = 1024, N = 1024;
    int z = blockIdx.z;
    const short* Xz = (const short*)(X + (size_t)z * zsX);
    const short* Wz = (const short*)(WT + (size_t)z * zsW);
    const float* bz = bias + (size_t)z * zsB;
    float* Cz = Cout + (size_t)z * zsC;

    // XCD-aware bijective swizzle (256 blocks per z-slice, 256 % 8 == 0)
    int bid = blockIdx.y * gridDim.x + blockIdx.x;
    int nb_cnt = gridDim.x * gridDim.y;
    int cpx = nb_cnt >> 3;
    int swz = (bid & 7) * cpx + (bid >> 3);
    int nb = swz % gridDim.x;
    int mb = swz / gridDim.x;
    int m0 = mb * 128;
    int n0 = nb * 128;

    // LDS union: main loop As/Bs = 32KB; epilogue wgT+xw = 36KB
    __shared__ short smem[18432];
    short* As = smem;            // [kk][128][32]
    short* Bs = smem + 8192;
    short* wgT = smem;           // [2][64][72]
    short* xw  = smem + 9216;    // [4 waves][32][72]

    int tid = threadIdx.x;
    int lane = tid & 63;
    int w = tid >> 6;
    int wm = (w >> 1) * 64, wn = (w & 1) * 64;

    f32x4 acc[4][4] = {};

    int srow = tid >> 2;
    int scol = (tid & 3) * 8;
    const short* Ag = Xz + (size_t)(m0 + srow) * K + scol;
    const short* Bg = Wz + (size_t)(n0 + srow) * K + scol;

    int fr = lane & 15, kg = (lane >> 4) * 8;

    for (int kt = 0; kt < K / 64; ++kt) {
        const short* Ak = Ag + kt * 64;
        const short* Bk = Bg + kt * 64;
        __syncthreads();
        gll16(Ak,                      As + tid * 8);
        gll16(Ak + (size_t)64 * K,     As + 2048 + tid * 8);
        gll16(Ak + 32,                 As + 4096 + tid * 8);
        gll16(Ak + 32 + (size_t)64 * K, As + 6144 + tid * 8);
        gll16(Bk,                      Bs + tid * 8);
        gll16(Bk + (size_t)64 * K,     Bs + 2048 + tid * 8);
        gll16(Bk + 32,                 Bs + 4096 + tid * 8);
        gll16(Bk + 32 + (size_t)64 * K, Bs + 6144 + tid * 8);
        __syncthreads();

#pragma unroll
        for (int kk = 0; kk < 2; ++kk) {
            short8 af[4], bf[4];
#pragma unroll
            for (int mi = 0; mi < 4; ++mi)
                af[mi] = *(const short8*)&As[kk * 4096 + (wm + mi * 16 + fr) * 32 + kg];
#pragma unroll
            for (int ni = 0; ni < 4; ++ni)
                bf[ni] = *(const short8*)&Bs[kk * 4096 + (wn + ni * 16 + fr) * 32 + kg];
#pragma unroll
            for (int mi = 0; mi < 4; ++mi)
#pragma unroll
                for (int ni = 0; ni < 4; ++ni)
                    acc[mi][ni] = __builtin_amdgcn_mfma_f32_16x16x32_bf16(af[mi], bf[ni], acc[mi][ni], 0, 0, 0);
        }
    }

    int g = lane >> 4, c4 = lane & 15;

    if (mode == 1 && z < 2) {
        // -------- fused phi epilogue (bf16 output) --------
        const float nd = 0.35355339059327373f;  // 64^-0.25
        unsigned short* O = (z == 0) ? qp_out : kp_out2;
        int h = nb * 2 + (w & 1);
        int b = m0 >> 11;
        float bias_n[4];
#pragma unroll
        for (int ni = 0; ni < 4; ++ni) bias_n[ni] = bz[n0 + wn + ni * 16 + c4];

        __syncthreads();
        {
            int row = tid >> 2, part = tid & 3;
#pragma unroll
            for (int hl = 0; hl < 2; ++hl) {
                const short* src = wgbT + ((size_t)(nb * 2 + hl)) * 4096 + row * 64 + part * 16;
                short8 v0 = *(const short8*)src;
                short8 v1 = *(const short8*)(src + 8);
                *(short8*)&wgT[hl * 4608 + row * 72 + part * 16] = v0;
                *(short8*)&wgT[hl * 4608 + row * 72 + part * 16 + 8] = v1;
            }
        }
        __syncthreads();

        short* xww = xw + w * 2304;
        const short* wgh = wgT + (w & 1) * 4608;

#pragma unroll
        for (int pass = 0; pass < 2; ++pass) {
            float nrm[2][4];
#pragma unroll
            for (int mi_l = 0; mi_l < 2; ++mi_l) {
                int mi = pass * 2 + mi_l;
                float part_n[4] = {0.f, 0.f, 0.f, 0.f};
#pragma unroll
                for (int ni = 0; ni < 4; ++ni)
#pragma unroll
                    for (int i = 0; i < 4; ++i) {
                        float xv = (acc[mi][ni][i] + bias_n[ni]) * nd;
                        part_n[i] += xv * xv;
                        xww[(mi_l * 16 + g * 4 + i) * 72 + ni * 16 + c4] = (short)f2bf(xv);
                    }
#pragma unroll
                for (int i = 0; i < 4; ++i) {
                    float t = part_n[i];
                    t += __shfl_xor(t, 1, 64);
                    t += __shfl_xor(t, 2, 64);
                    t += __shfl_xor(t, 4, 64);
                    t += __shfl_xor(t, 8, 64);
                    nrm[mi_l][i] = t;
                }
            }
            short8 afr[2][2], bfr[4][2];
#pragma unroll
            for (int mi_l = 0; mi_l < 2; ++mi_l)
#pragma unroll
                for (int kk = 0; kk < 2; ++kk)
                    afr[mi_l][kk] = *(const short8*)&xww[(mi_l * 16 + c4) * 72 + kk * 32 + g * 8];
#pragma unroll
            for (int ri = 0; ri < 4; ++ri)
#pragma unroll
                for (int kk = 0; kk < 2; ++kk)
                    bfr[ri][kk] = *(const short8*)&wgh[(ri * 16 + c4) * 72 + kk * 32 + g * 8];
            f32x4 p[2][4] = {};
#pragma unroll
            for (int mi_l = 0; mi_l < 2; ++mi_l)
#pragma unroll
                for (int ri = 0; ri < 4; ++ri)
#pragma unroll
                    for (int kk = 0; kk < 2; ++kk)
                        p[mi_l][ri] = __builtin_amdgcn_mfma_f32_16x16x32_bf16(afr[mi_l][kk], bfr[ri][kk], p[mi_l][ri], 0, 0, 0);
#pragma unroll
            for (int mi_l = 0; mi_l < 2; ++mi_l)
#pragma unroll
                for (int ri = 0; ri < 4; ++ri)
#pragma unroll
                    for (int i = 0; i < 4; ++i) {
                        int mi = pass * 2 + mi_l;
                        float val = 0.125f * __expf(p[mi_l][ri][i] - 0.5f * nrm[mi_l][i]);
                        int row = m0 + wm + mi * 16 + g * 4 + i;
                        int s = row & 2047;
                        O[((size_t)(b * 16 + h) * SS + s) * RR + ri * 16 + c4] = f2bf(val);
                    }
        }
        return;
    }

    int rg = g * 4;
    if (mode == 1) {
        // -------- vh epilogue: bf16 --------
        unsigned short* Cz16 = (unsigned short*)Cz;
#pragma unroll
        for (int mi = 0; mi < 4; ++mi)
#pragma unroll
            for (int ni = 0; ni < 4; ++ni) {
                int gn = n0 + wn + ni * 16 + fr;
                float bval = bz[gn];
#pragma unroll
                for (int i = 0; i < 4; ++i) {
                    int gm = m0 + wm + mi * 16 + rg + i;
                    Cz16[(size_t)gm * N + gn] = f2bf(acc[mi][ni][i] + bval);
                }
            }
        return;
    }

    // -------- plain f32 epilogue (final output GEMM) --------
#pragma unroll
    for (int mi = 0; mi < 4; ++mi)
#pragma unroll
        for (int ni = 0; ni < 4; ++ni) {
            int gn = n0 + wn + ni * 16 + fr;
            float bval = bz[gn];
#pragma unroll
            for (int i = 0; i < 4; ++i) {
                int gm = m0 + wm + mi * 16 + rg + i;
                Cz[(size_t)gm * N + gn] = acc[mi][ni][i] + bval;
            }
        }
}

// ---------------- chunk sums (bf16 inputs staged to f32 LDS; cs stored bf16) ----------------
__global__ __launch_bounds__(64) void k_chunksum(
    const unsigned short* __restrict__ kprime, const unsigned short* __restrict__ vh,
    unsigned short* __restrict__ cs)
{
    int c = blockIdx.x;
    int bh = blockIdx.y;
    int b = bh >> 4, h = bh & 15;
    int lane = threadIdx.x;
    __shared__ float kp[CH][RR];
    __shared__ float vv[CH][RR];
    size_t rowbase = (size_t)bh * SS + c * CH;
    const unsigned short* kpb = kprime + rowbase * RR;
    const unsigned short* vb = vh + ((size_t)b * SS + c * CH) * DD + h * DH;
#pragma unroll
    for (int i = 0; i < 4; ++i) {
        int flat = i * 64 + lane;          // 256 granules of 8 bf16
        int row = flat >> 3, c8 = (flat & 7) * 8;
        short8 k8 = *(const short8*)(kpb + (size_t)row * RR + c8);
        short8 v8 = *(const short8*)(vb + (size_t)row * DD + c8);
#pragma unroll
        for (int e = 0; e < 8; ++e) {
            kp[row][c8 + e] = bf2f((unsigned short)k8[e]);
            vv[row][c8 + e] = bf2f((unsigned short)v8[e]);
        }
    }
    __syncthreads();

    float st[RR];
#pragma unroll
    for (int r = 0; r < RR; ++r) st[r] = 0.f;
    float kpsum = 0.f;
    for (int s = 0; s < CH; ++s) {
        float vd = vv[s][lane];
        kpsum += kp[s][lane];
#pragma unroll
        for (int rq = 0; rq < RR / 4; ++rq) {
            f32x4 kq = *(const f32x4*)&kp[s][rq * 4];
            st[rq * 4 + 0] += kq[0] * vd;
            st[rq * 4 + 1] += kq[1] * vd;
            st[rq * 4 + 2] += kq[2] * vd;
            st[rq * 4 + 3] += kq[3] * vd;
        }
    }
    unsigned short* out = cs + (size_t)(bh * NCH + c) * CSROW;
#pragma unroll
    for (int r = 0; r < RR; ++r) out[r * 64 + lane] = f2bf(st[r]);
    out[4096 + lane] = f2bf(kpsum);
}

// ---------------- exclusive scan over chunks (bf16 storage, f32 accumulator) ----------------
__global__ __launch_bounds__(256) void k_scan(unsigned short* __restrict__ cs)
{
    int t = blockIdx.x * 256 + threadIdx.x;
    if (t >= BH * CSROW) return;
    int bh = t / CSROW;
    int e = t - bh * CSROW;
    unsigned short* p = cs + (size_t)bh * NCH * CSROW + e;
    unsigned short v[NCH];
#pragma unroll
    for (int c = 0; c < NCH; ++c) v[c] = p[(size_t)c * CSROW];
    float run = 0.f;
#pragma unroll
    for (int c = 0; c < NCH; ++c) {
        float x = bf2f(v[c]);
        p[(size_t)c * CSROW] = f2bf(run);
        run += x;
    }
}

// ---------------- final: bf16 inputs staged; s-loop is a near-pure write stream ----------------
__global__ __launch_bounds__(64) void k_scanfinal(
    const unsigned short* __restrict__ kprime, const unsigned short* __restrict__ qprime,
    const unsigned short* __restrict__ vh, const unsigned short* __restrict__ cs,
    float* __restrict__ kp_out, float* __restrict__ kv_out,
    __hip_bfloat16* __restrict__ attnb)
{
    int c = blockIdx.x;
    int bh = blockIdx.y;
    int b = bh >> 4, h = bh & 15;
    int lane = threadIdx.x;
    int g = lane >> 4, c4 = lane & 15;
    __shared__ float kp[CH][RR];
    __shared__ float qp[CH][RR];
    __shared__ float vv[CH][RR];
    size_t rowbase = (size_t)bh * SS + c * CH;
    const unsigned short* kpb = kprime + rowbase * RR;
    const unsigned short* qpb = qprime + rowbase * RR;
    const unsigned short* vb = vh + ((size_t)b * SS + c * CH) * DD + h * DH;
#pragma unroll
    for (int i = 0; i < 4; ++i) {
        int flat = i * 64 + lane;
        int row = flat >> 3, c8 = (flat & 7) * 8;
        short8 k8 = *(const short8*)(kpb + (size_t)row * RR + c8);
        short8 q8 = *(const short8*)(qpb + (size_t)row * RR + c8);
        short8 v8 = *(const short8*)(vb + (size_t)row * DD + c8);
#pragma unroll
        for (int e = 0; e < 8; ++e) {
            kp[row][c8 + e] = bf2f((unsigned short)k8[e]);
            qp[row][c8 + e] = bf2f((unsigned short)q8[e]);
            vv[row][c8 + e] = bf2f((unsigned short)v8[e]);
        }
    }

    const unsigned short* off = cs + (size_t)(bh * NCH + c) * CSROW;
    f32x4 st[16];
#pragma unroll
    for (int j = 0; j < 16; ++j) {
        ushort4 u = *(const ushort4*)&off[(4 * j + g) * 64 + 4 * c4];
        st[j][0] = bf2f(u.x); st[j][1] = bf2f(u.y);
        st[j][2] = bf2f(u.z); st[j][3] = bf2f(u.w);
    }
    float kps = bf2f(off[4096 + lane]);
    __syncthreads();

    for (int s = 0; s < CH; ++s) {
        float kpl = kp[s][lane];
        kps += kpl;
        size_t srow = rowbase + s;
        kp_out[srow * RR + lane] = kps;

        float qksum = qp[s][lane] * kps;
#pragma unroll
        for (int m = 1; m < 64; m <<= 1) qksum += __shfl_xor(qksum, m, 64);

        f32x4 v4 = *(const f32x4*)&vv[s][4 * c4];
        f32x4 accp = {0.f, 0.f, 0.f, 0.f};
        float* kvp = kv_out + srow * (size_t)(RR * DH);
#pragma unroll
        for (int j = 0; j < 16; ++j) {
            float kpj = kp[s][4 * j + g];
            float qpj = qp[s][4 * j + g];
            st[j] += kpj * v4;
            __builtin_nontemporal_store(st[j], (f32x4*)(kvp + (4 * j + g) * 64 + 4 * c4));
            accp += qpj * st[j];
        }
#pragma unroll
        for (int e = 0; e < 4; ++e) {
            accp[e] += __shfl_xor(accp[e], 16, 64);
            accp[e] += __shfl_xor(accp[e], 32, 64);
        }
        float rs = 1.0f / (1e-6f + qksum);
        if (g == 0) {
            ushort4 pkt;
            pkt.x = f2bf(accp[0] * rs);
            pkt.y = f2bf(accp[1] * rs);
            pkt.z = f2bf(accp[2] * rs);
            pkt.w = f2bf(accp[3] * rs);
            *(ushort4*)((unsigned short*)attnb + ((size_t)b * SS + c * CH + s) * DD + h * DH + 4 * c4) = pkt;
        }
    }
}

extern "C" void kernel_launch(void* const* d_in, const int* in_sizes, int n_in,
                              void* d_out, int out_size, void* d_ws, size_t ws_size,
                              hipStream_t stream) {
    const float* v_in  = (const float*)d_in[0];
    const float* k_in  = (const float*)d_in[1];
    const float* q_in  = (const float*)d_in[2];
    const float* wq_w  = (const float*)d_in[3];
    const float* wq_b  = (const float*)d_in[4];
    const float* wk_w  = (const float*)d_in[5];
    const float* wk_b  = (const float*)d_in[6];
    const float* wv_w  = (const float*)d_in[7];
    const float* wv_b  = (const float*)d_in[8];
    const float* wc_w  = (const float*)d_in[9];
    const float* wc_b  = (const float*)d_in[10];
    const float* wg    = (const float*)d_in[11];

    char* ws = (char*)d_ws;
    __hip_bfloat16* Xb    = (__hip_bfloat16*)(ws + 0);          // [3][4096][1024] bf16
    __hip_bfloat16* WT    = (__hip_bfloat16*)(ws + 25165824);   // [3][1024][1024] bf16
    __hip_bfloat16* wcT   = (__hip_bfloat16*)(ws + 31457280);   // [1024][1024] bf16
    float* biasb          = (float*)(ws + 33554432);            // [3][1024]
    float* qhkv           = (float*)(ws + 33570816);            // f32 slots (z=2 holds bf16 vh)
    unsigned short* qprime = (unsigned short*)(ws + 83902464);  // [32][2048][64] bf16
    unsigned short* kprime = (unsigned short*)(ws + 100679680); // [32][2048][64] bf16
    unsigned short* cs    = (unsigned short*)(ws + 117456896);  // [32][64][4160] bf16
    __hip_bfloat16* attnb = (__hip_bfloat16*)(ws + 151535616);  // [4096][1024] bf16
    short* wgbT           = (short*)(ws + 159924224);           // [16][64][64] bf16

    float* kp_out = (float*)d_out;                 // [32][2048][64]
    float* kv_out = kp_out + 4194304;              // [32][2048][64][64]
    float* out_o  = kv_out + 268435456;            // [4096][1024]
    unsigned short* vh16 = (unsigned short*)(qhkv + 2 * 4194304);

    k_pre<<<dim3(13328), 256, 0, stream>>>(q_in, k_in, v_in, wq_b, wk_b, wv_b,
                                           wq_w, wk_w, wv_w, wc_w, wg,
                                           Xb, biasb, WT, wcT, wgbT);
    gemm_bt<<<dim3(8, 32, 3), 256, 0, stream>>>(Xb, WT, biasb, qhkv, wgbT, qprime, kprime,
                                                4194304L, 1048576L, 1024L, 4194304L, 1);
    k_chunksum<<<dim3(NCH, BH), 64, 0, stream>>>(kprime, vh16, cs);
    k_scan<<<dim3(520), 256, 0, stream>>>(cs);
    k_scanfinal<<<dim3(NCH, BH), 64, 0, stream>>>(kprime, qprime, vh16, cs,
                                                  kp_out, kv_out, attnb);
    gemm_bt<<<dim3(8, 32, 1), 256, 0, stream>>>(attnb, wcT, wc_b, out_o, wgbT, qprime, kprime,
                                                0L, 0L, 0L, 0L, 0);
}

// Round 9
// 319.360 us; speedup vs baseline: 1.0537x; 1.0180x over previous
//
#include <hip/hip_runtime.h>
#include <hip/hip_bf16.h>

#define BB 2
#define SS 2048
#define DD 1024
#define HH 16
#define RR 64
#define DH 64
#define BH (BB*HH)      // 32
#define MM (BB*SS)      // 4096
#define CH 32
#define NCH (SS/CH)     // 64
#define CSROW (RR*DH + RR)  // 4160

using short8 = __attribute__((ext_vector_type(8))) short;
using f32x4  = __attribute__((ext_vector_type(4))) float;

typedef const __attribute__((address_space(1))) unsigned int* gp_t;
typedef __attribute__((address_space(3))) unsigned int* lp_t;

__device__ __forceinline__ void gll16(const void* g, void* l) {
    __builtin_amdgcn_global_load_lds((gp_t)g, (lp_t)l, 16, 0, 0);
}

__device__ __forceinline__ unsigned short f2bf(float x) {
    __hip_bfloat16 h = __float2bfloat16(x);
    return *(unsigned short*)&h;
}

__device__ __forceinline__ float bf2f(unsigned short u) {
    return __uint_as_float(((unsigned int)u) << 16);
}

// ---------------- fused pre (flattened 1D grid) ----------------
__global__ __launch_bounds__(256) void k_pre(
    const float* __restrict__ q, const float* __restrict__ k, const float* __restrict__ v,
    const float* __restrict__ bq, const float* __restrict__ bk, const float* __restrict__ bv,
    const float* __restrict__ wq, const float* __restrict__ wk,
    const float* __restrict__ wv, const float* __restrict__ wc,
    const float* __restrict__ wg,
    __hip_bfloat16* __restrict__ Xb, float* __restrict__ biasb,
    __hip_bfloat16* __restrict__ WT, __hip_bfloat16* __restrict__ wcT,
    short* __restrict__ wgbT)
{
    int bid = blockIdx.x;
    __shared__ float tile[64][65];
    if (bid < 12288) {
        int z = bid >> 12;
        int bx = bid & 4095;
        const float* src = (z == 0) ? q : (z == 1) ? k : v;
        size_t i = ((size_t)bx * 256 + threadIdx.x) * 4;
        float4 f = *(const float4*)(src + i);
        __hip_bfloat16* dst = Xb + (size_t)z * 4194304 + i;
        dst[0] = __float2bfloat16(f.x);
        dst[1] = __float2bfloat16(f.y);
        dst[2] = __float2bfloat16(f.z);
        dst[3] = __float2bfloat16(f.w);
        if (bx == 0) {
            const float* bb = (z == 0) ? bq : (z == 1) ? bk : bv;
            for (int t = threadIdx.x; t < 1024; t += 256)
                biasb[z * 1024 + t] = bb[t];
        }
    } else if (bid < 13312) {
        int sub = bid - 12288;
        int zz = sub >> 8;
        sub &= 255;
        const float* W = (zz == 0) ? wq : (zz == 1) ? wk : (zz == 2) ? wv : wc;
        __hip_bfloat16* T = (zz < 3) ? (WT + (size_t)zz * 1048576) : wcT;
        int k0 = (sub >> 4) * 64, n0 = (sub & 15) * 64;
        for (int i = threadIdx.x; i < 4096; i += 256) {
            int r = i >> 6, cc = i & 63;
            tile[r][cc] = W[(size_t)(k0 + r) * 1024 + n0 + cc];
        }
        __syncthreads();
        for (int i = threadIdx.x; i < 4096; i += 256) {
            int nl = i >> 6, kl = i & 63;
            T[(size_t)(n0 + nl) * 1024 + k0 + kl] = __float2bfloat16(tile[kl][nl]);
        }
    } else {
        int hx = bid - 13312;
        for (int i = threadIdx.x; i < 4096; i += 256)
            tile[i >> 6][i & 63] = wg[(size_t)hx * 4096 + i];   // tile[d][r]
        __syncthreads();
        for (int i = threadIdx.x; i < 4096; i += 256) {
            int r = i >> 6, d = i & 63;
            wgbT[(size_t)hx * 4096 + r * 64 + d] = (short)f2bf(tile[d][r]);
        }
    }
}

// ---------------- GEMM1, BK=64, XCD-swizzled, fused phi / bf16-vh epilogues ----------------
__global__ __launch_bounds__(256) void gemm_bt(
    const __hip_bfloat16* __restrict__ X, const __hip_bfloat16* __restrict__ WT,
    const float* __restrict__ bias, float* __restrict__ Cout,
    const short* __restrict__ wgbT,
    unsigned short* __restrict__ qp_out, unsigned short* __restrict__ kp_out2,
    long zsX, long zsW, long zsB, long zsC, int mode)
{
    const int K = 1024, N = 1024;
    int z = blockIdx.z;
    const short* Xz = (const short*)(X + (size_t)z * zsX);
    const short* Wz = (const short*)(WT + (size_t)z * zsW);
    const float* bz = bias + (size_t)z * zsB;
    float* Cz = Cout + (size_t)z * zsC;

    // XCD-aware bijective swizzle (256 blocks per z-slice, 256 % 8 == 0)
    int bid = blockIdx.y * gridDim.x + blockIdx.x;
    int nb_cnt = gridDim.x * gridDim.y;
    int cpx = nb_cnt >> 3;
    int swz = (bid & 7) * cpx + (bid >> 3);
    int nb = swz % gridDim.x;
    int mb = swz / gridDim.x;
    int m0 = mb * 128;
    int n0 = nb * 128;

    // LDS union: main loop As/Bs = 32KB; epilogue wgT+xw = 36KB
    __shared__ short smem[18432];
    short* As = smem;            // [kk][128][32]
    short* Bs = smem + 8192;
    short* wgT = smem;           // [2][64][72]
    short* xw  = smem + 9216;    // [4 waves][32][72]

    int tid = threadIdx.x;
    int lane = tid & 63;
    int w = tid >> 6;
    int wm = (w >> 1) * 64, wn = (w & 1) * 64;

    f32x4 acc[4][4] = {};

    int srow = tid >> 2;
    int scol = (tid & 3) * 8;
    const short* Ag = Xz + (size_t)(m0 + srow) * K + scol;
    const short* Bg = Wz + (size_t)(n0 + srow) * K + scol;

    int fr = lane & 15, kg = (lane >> 4) * 8;

    for (int kt = 0; kt < K / 64; ++kt) {
        const short* Ak = Ag + kt * 64;
        const short* Bk = Bg + kt * 64;
        __syncthreads();
        gll16(Ak,                      As + tid * 8);
        gll16(Ak + (size_t)64 * K,     As + 2048 + tid * 8);
        gll16(Ak + 32,                 As + 4096 + tid * 8);
        gll16(Ak + 32 + (size_t)64 * K, As + 6144 + tid * 8);
        gll16(Bk,                      Bs + tid * 8);
        gll16(Bk + (size_t)64 * K,     Bs + 2048 + tid * 8);
        gll16(Bk + 32,                 Bs + 4096 + tid * 8);
        gll16(Bk + 32 + (size_t)64 * K, Bs + 6144 + tid * 8);
        __syncthreads();

#pragma unroll
        for (int kk = 0; kk < 2; ++kk) {
            short8 af[4], bf[4];
#pragma unroll
            for (int mi = 0; mi < 4; ++mi)
                af[mi] = *(const short8*)&As[kk * 4096 + (wm + mi * 16 + fr) * 32 + kg];
#pragma unroll
            for (int ni = 0; ni < 4; ++ni)
                bf[ni] = *(const short8*)&Bs[kk * 4096 + (wn + ni * 16 + fr) * 32 + kg];
#pragma unroll
            for (int mi = 0; mi < 4; ++mi)
#pragma unroll
                for (int ni = 0; ni < 4; ++ni)
                    acc[mi][ni] = __builtin_amdgcn_mfma_f32_16x16x32_bf16(af[mi], bf[ni], acc[mi][ni], 0, 0, 0);
        }
    }

    int g = lane >> 4, c4 = lane & 15;

    if (mode == 1 && z < 2) {
        // -------- fused phi epilogue (bf16 output) --------
        const float nd = 0.35355339059327373f;  // 64^-0.25
        unsigned short* O = (z == 0) ? qp_out : kp_out2;
        int h = nb * 2 + (w & 1);
        int b = m0 >> 11;
        float bias_n[4];
#pragma unroll
        for (int ni = 0; ni < 4; ++ni) bias_n[ni] = bz[n0 + wn + ni * 16 + c4];

        __syncthreads();
        {
            int row = tid >> 2, part = tid & 3;
#pragma unroll
            for (int hl = 0; hl < 2; ++hl) {
                const short* src = wgbT + ((size_t)(nb * 2 + hl)) * 4096 + row * 64 + part * 16;
                short8 v0 = *(const short8*)src;
                short8 v1 = *(const short8*)(src + 8);
                *(short8*)&wgT[hl * 4608 + row * 72 + part * 16] = v0;
                *(short8*)&wgT[hl * 4608 + row * 72 + part * 16 + 8] = v1;
            }
        }
        __syncthreads();

        short* xww = xw + w * 2304;
        const short* wgh = wgT + (w & 1) * 4608;

#pragma unroll
        for (int pass = 0; pass < 2; ++pass) {
            float nrm[2][4];
#pragma unroll
            for (int mi_l = 0; mi_l < 2; ++mi_l) {
                int mi = pass * 2 + mi_l;
                float part_n[4] = {0.f, 0.f, 0.f, 0.f};
#pragma unroll
                for (int ni = 0; ni < 4; ++ni)
#pragma unroll
                    for (int i = 0; i < 4; ++i) {
                        float xv = (acc[mi][ni][i] + bias_n[ni]) * nd;
                        part_n[i] += xv * xv;
                        xww[(mi_l * 16 + g * 4 + i) * 72 + ni * 16 + c4] = (short)f2bf(xv);
                    }
#pragma unroll
                for (int i = 0; i < 4; ++i) {
                    float t = part_n[i];
                    t += __shfl_xor(t, 1, 64);
                    t += __shfl_xor(t, 2, 64);
                    t += __shfl_xor(t, 4, 64);
                    t += __shfl_xor(t, 8, 64);
                    nrm[mi_l][i] = t;
                }
            }
            short8 afr[2][2], bfr[4][2];
#pragma unroll
            for (int mi_l = 0; mi_l < 2; ++mi_l)
#pragma unroll
                for (int kk = 0; kk < 2; ++kk)
                    afr[mi_l][kk] = *(const short8*)&xww[(mi_l * 16 + c4) * 72 + kk * 32 + g * 8];
#pragma unroll
            for (int ri = 0; ri < 4; ++ri)
#pragma unroll
                for (int kk = 0; kk < 2; ++kk)
                    bfr[ri][kk] = *(const short8*)&wgh[(ri * 16 + c4) * 72 + kk * 32 + g * 8];
            f32x4 p[2][4] = {};
#pragma unroll
            for (int mi_l = 0; mi_l < 2; ++mi_l)
#pragma unroll
                for (int ri = 0; ri < 4; ++ri)
#pragma unroll
                    for (int kk = 0; kk < 2; ++kk)
                        p[mi_l][ri] = __builtin_amdgcn_mfma_f32_16x16x32_bf16(afr[mi_l][kk], bfr[ri][kk], p[mi_l][ri], 0, 0, 0);
#pragma unroll
            for (int mi_l = 0; mi_l < 2; ++mi_l)
#pragma unroll
                for (int ri = 0; ri < 4; ++ri)
#pragma unroll
                    for (int i = 0; i < 4; ++i) {
                        int mi = pass * 2 + mi_l;
                        float val = 0.125f * __expf(p[mi_l][ri][i] - 0.5f * nrm[mi_l][i]);
                        int row = m0 + wm + mi * 16 + g * 4 + i;
                        int s = row & 2047;
                        O[((size_t)(b * 16 + h) * SS + s) * RR + ri * 16 + c4] = f2bf(val);
                    }
        }
        return;
    }

    int rg = g * 4;
    // -------- vh epilogue: bf16 --------
    unsigned short* Cz16 = (unsigned short*)Cz;
#pragma unroll
    for (int mi = 0; mi < 4; ++mi)
#pragma unroll
        for (int ni = 0; ni < 4; ++ni) {
            int gn = n0 + wn + ni * 16 + fr;
            float bval = bz[gn];
#pragma unroll
            for (int i = 0; i < 4; ++i) {
                int gm = m0 + wm + mi * 16 + rg + i;
                Cz16[(size_t)gm * N + gn] = f2bf(acc[mi][ni][i] + bval);
            }
        }
}

// ---------------- GEMM2 (output projection): BM=64, BN=128 -> 512 blocks = 2/CU ----------------
__global__ __launch_bounds__(256) void gemm_out(
    const __hip_bfloat16* __restrict__ X,   // attnb [4096][1024] bf16
    const __hip_bfloat16* __restrict__ WT,  // wcT [1024(n)][1024(k)] bf16
    const float* __restrict__ bias, float* __restrict__ C)
{
    const int K = 1024, N = 1024;
    // grid (8, 64) = 512 blocks; bijective XCD swizzle (512 % 8 == 0)
    int bid = blockIdx.y * gridDim.x + blockIdx.x;
    int nb_cnt = gridDim.x * gridDim.y;
    int cpx = nb_cnt >> 3;
    int swz = (bid & 7) * cpx + (bid >> 3);
    int nb = swz % gridDim.x;
    int mb = swz / gridDim.x;
    int m0 = mb * 64;
    int n0 = nb * 128;

    __shared__ short As[2 * 64 * 32];    // [kk][64][32]  : 8KB
    __shared__ short Bs[2 * 128 * 32];   // [kk][128][32] : 16KB

    int tid = threadIdx.x;
    int lane = tid & 63;
    int w = tid >> 6;
    int wm = (w >> 1) * 32, wn = (w & 1) * 64;

    f32x4 acc[2][4] = {};

    int srow = tid >> 2;
    int scol = (tid & 3) * 8;
    const short* Ag = (const short*)X + (size_t)(m0 + srow) * K + scol;
    const short* Bg = (const short*)WT + (size_t)(n0 + srow) * K + scol;

    int fr = lane & 15, kg = (lane >> 4) * 8;

    for (int kt = 0; kt < K / 64; ++kt) {
        const short* Ak = Ag + kt * 64;
        const short* Bk = Bg + kt * 64;
        __syncthreads();
        gll16(Ak,                       As + tid * 8);          // kk0 rows 0-63
        gll16(Ak + 32,                  As + 2048 + tid * 8);   // kk1 rows 0-63
        gll16(Bk,                       Bs + tid * 8);          // kk0 rows 0-63
        gll16(Bk + (size_t)64 * K,      Bs + 2048 + tid * 8);   // kk0 rows 64-127
        gll16(Bk + 32,                  Bs + 4096 + tid * 8);   // kk1 rows 0-63
        gll16(Bk + 32 + (size_t)64 * K, Bs + 6144 + tid * 8);   // kk1 rows 64-127
        __syncthreads();

#pragma unroll
        for (int kk = 0; kk < 2; ++kk) {
            short8 af[2], bf[4];
#pragma unroll
            for (int mi = 0; mi < 2; ++mi)
                af[mi] = *(const short8*)&As[kk * 2048 + (wm + mi * 16 + fr) * 32 + kg];
#pragma unroll
            for (int ni = 0; ni < 4; ++ni)
                bf[ni] = *(const short8*)&Bs[kk * 4096 + (wn + ni * 16 + fr) * 32 + kg];
#pragma unroll
            for (int mi = 0; mi < 2; ++mi)
#pragma unroll
                for (int ni = 0; ni < 4; ++ni)
                    acc[mi][ni] = __builtin_amdgcn_mfma_f32_16x16x32_bf16(af[mi], bf[ni], acc[mi][ni], 0, 0, 0);
        }
    }

    int g = lane >> 4, c4 = lane & 15, rg = g * 4;
#pragma unroll
    for (int mi = 0; mi < 2; ++mi)
#pragma unroll
        for (int ni = 0; ni < 4; ++ni) {
            int gn = n0 + wn + ni * 16 + c4;
            float bval = bias[gn];
#pragma unroll
            for (int i = 0; i < 4; ++i) {
                int gm = m0 + wm + mi * 16 + rg + i;
                C[(size_t)gm * N + gn] = acc[mi][ni][i] + bval;
            }
        }
}

// ---------------- chunk sums (bf16 inputs staged to f32 LDS; cs stored bf16) ----------------
__global__ __launch_bounds__(64) void k_chunksum(
    const unsigned short* __restrict__ kprime, const unsigned short* __restrict__ vh,
    unsigned short* __restrict__ cs)
{
    int c = blockIdx.x;
    int bh = blockIdx.y;
    int b = bh >> 4, h = bh & 15;
    int lane = threadIdx.x;
    __shared__ float kp[CH][RR];
    __shared__ float vv[CH][RR];
    size_t rowbase = (size_t)bh * SS + c * CH;
    const unsigned short* kpb = kprime + rowbase * RR;
    const unsigned short* vb = vh + ((size_t)b * SS + c * CH) * DD + h * DH;
#pragma unroll
    for (int i = 0; i < 4; ++i) {
        int flat = i * 64 + lane;          // 256 granules of 8 bf16
        int row = flat >> 3, c8 = (flat & 7) * 8;
        short8 k8 = *(const short8*)(kpb + (size_t)row * RR + c8);
        short8 v8 = *(const short8*)(vb + (size_t)row * DD + c8);
#pragma unroll
        for (int e = 0; e < 8; ++e) {
            kp[row][c8 + e] = bf2f((unsigned short)k8[e]);
            vv[row][c8 + e] = bf2f((unsigned short)v8[e]);
        }
    }
    __syncthreads();

    float st[RR];
#pragma unroll
    for (int r = 0; r < RR; ++r) st[r] = 0.f;
    float kpsum = 0.f;
    for (int s = 0; s < CH; ++s) {
        float vd = vv[s][lane];
        kpsum += kp[s][lane];
#pragma unroll
        for (int rq = 0; rq < RR / 4; ++rq) {
            f32x4 kq = *(const f32x4*)&kp[s][rq * 4];
            st[rq * 4 + 0] += kq[0] * vd;
            st[rq * 4 + 1] += kq[1] * vd;
            st[rq * 4 + 2] += kq[2] * vd;
            st[rq * 4 + 3] += kq[3] * vd;
        }
    }
    unsigned short* out = cs + (size_t)(bh * NCH + c) * CSROW;
#pragma unroll
    for (int r = 0; r < RR; ++r) out[r * 64 + lane] = f2bf(st[r]);
    out[4096 + lane] = f2bf(kpsum);
}

// ---------------- exclusive scan over chunks (bf16 storage, f32 accumulator) ----------------
__global__ __launch_bounds__(256) void k_scan(unsigned short* __restrict__ cs)
{
    int t = blockIdx.x * 256 + threadIdx.x;
    if (t >= BH * CSROW) return;
    int bh = t / CSROW;
    int e = t - bh * CSROW;
    unsigned short* p = cs + (size_t)bh * NCH * CSROW + e;
    unsigned short v[NCH];
#pragma unroll
    for (int c = 0; c < NCH; ++c) v[c] = p[(size_t)c * CSROW];
    float run = 0.f;
#pragma unroll
    for (int c = 0; c < NCH; ++c) {
        float x = bf2f(v[c]);
        p[(size_t)c * CSROW] = f2bf(run);
        run += x;
    }
}

// ---------------- final: bf16 inputs staged; s-loop is a near-pure write stream ----------------
__global__ __launch_bounds__(64) void k_scanfinal(
    const unsigned short* __restrict__ kprime, const unsigned short* __restrict__ qprime,
    const unsigned short* __restrict__ vh, const unsigned short* __restrict__ cs,
    float* __restrict__ kp_out, float* __restrict__ kv_out,
    __hip_bfloat16* __restrict__ attnb)
{
    int c = blockIdx.x;
    int bh = blockIdx.y;
    int b = bh >> 4, h = bh & 15;
    int lane = threadIdx.x;
    int g = lane >> 4, c4 = lane & 15;
    __shared__ float kp[CH][RR];
    __shared__ float qp[CH][RR];
    __shared__ float vv[CH][RR];
    size_t rowbase = (size_t)bh * SS + c * CH;
    const unsigned short* kpb = kprime + rowbase * RR;
    const unsigned short* qpb = qprime + rowbase * RR;
    const unsigned short* vb = vh + ((size_t)b * SS + c * CH) * DD + h * DH;
#pragma unroll
    for (int i = 0; i < 4; ++i) {
        int flat = i * 64 + lane;
        int row = flat >> 3, c8 = (flat & 7) * 8;
        short8 k8 = *(const short8*)(kpb + (size_t)row * RR + c8);
        short8 q8 = *(const short8*)(qpb + (size_t)row * RR + c8);
        short8 v8 = *(const short8*)(vb + (size_t)row * DD + c8);
#pragma unroll
        for (int e = 0; e < 8; ++e) {
            kp[row][c8 + e] = bf2f((unsigned short)k8[e]);
            qp[row][c8 + e] = bf2f((unsigned short)q8[e]);
            vv[row][c8 + e] = bf2f((unsigned short)v8[e]);
        }
    }

    const unsigned short* off = cs + (size_t)(bh * NCH + c) * CSROW;
    f32x4 st[16];
#pragma unroll
    for (int j = 0; j < 16; ++j) {
        ushort4 u = *(const ushort4*)&off[(4 * j + g) * 64 + 4 * c4];
        st[j][0] = bf2f(u.x); st[j][1] = bf2f(u.y);
        st[j][2] = bf2f(u.z); st[j][3] = bf2f(u.w);
    }
    float kps = bf2f(off[4096 + lane]);
    __syncthreads();

    for (int s = 0; s < CH; ++s) {
        float kpl = kp[s][lane];
        kps += kpl;
        size_t srow = rowbase + s;
        kp_out[srow * RR + lane] = kps;

        float qksum = qp[s][lane] * kps;
#pragma unroll
        for (int m = 1; m < 64; m <<= 1) qksum += __shfl_xor(qksum, m, 64);

        f32x4 v4 = *(const f32x4*)&vv[s][4 * c4];
        f32x4 accp = {0.f, 0.f, 0.f, 0.f};
        float* kvp = kv_out + srow * (size_t)(RR * DH);
#pragma unroll
        for (int j = 0; j < 16; ++j) {
            float kpj = kp[s][4 * j + g];
            float qpj = qp[s][4 * j + g];
            st[j] += kpj * v4;
            __builtin_nontemporal_store(st[j], (f32x4*)(kvp + (4 * j + g) * 64 + 4 * c4));
            accp += qpj * st[j];
        }
#pragma unroll
        for (int e = 0; e < 4; ++e) {
            accp[e] += __shfl_xor(accp[e], 16, 64);
            accp[e] += __shfl_xor(accp[e], 32, 64);
        }
        float rs = 1.0f / (1e-6f + qksum);
        if (g == 0) {
            ushort4 pkt;
            pkt.x = f2bf(accp[0] * rs);
            pkt.y = f2bf(accp[1] * rs);
            pkt.z = f2bf(accp[2] * rs);
            pkt.w = f2bf(accp[3] * rs);
            *(ushort4*)((unsigned short*)attnb + ((size_t)b * SS + c * CH + s) * DD + h * DH + 4 * c4) = pkt;
        }
    }
}

extern "C" void kernel_launch(void* const* d_in, const int* in_sizes, int n_in,
                              void* d_out, int out_size, void* d_ws, size_t ws_size,
                              hipStream_t stream) {
    const float* v_in  = (const float*)d_in[0];
    const float* k_in  = (const float*)d_in[1];
    const float* q_in  = (const float*)d_in[2];
    const float* wq_w  = (const float*)d_in[3];
    const float* wq_b  = (const float*)d_in[4];
    const float* wk_w  = (const float*)d_in[5];
    const float* wk_b  = (const float*)d_in[6];
    const float* wv_w  = (const float*)d_in[7];
    const float* wv_b  = (const float*)d_in[8];
    const float* wc_w  = (const float*)d_in[9];
    const float* wc_b  = (const float*)d_in[10];
    const float* wg    = (const float*)d_in[11];

    char* ws = (char*)d_ws;
    __hip_bfloat16* Xb    = (__hip_bfloat16*)(ws + 0);          // [3][4096][1024] bf16
    __hip_bfloat16* WT    = (__hip_bfloat16*)(ws + 25165824);   // [3][1024][1024] bf16
    __hip_bfloat16* wcT   = (__hip_bfloat16*)(ws + 31457280);   // [1024][1024] bf16
    float* biasb          = (float*)(ws + 33554432);            // [3][1024]
    float* qhkv           = (float*)(ws + 33570816);            // f32 slots (z=2 holds bf16 vh)
    unsigned short* qprime = (unsigned short*)(ws + 83902464);  // [32][2048][64] bf16
    unsigned short* kprime = (unsigned short*)(ws + 100679680); // [32][2048][64] bf16
    unsigned short* cs    = (unsigned short*)(ws + 117456896);  // [32][64][4160] bf16
    __hip_bfloat16* attnb = (__hip_bfloat16*)(ws + 151535616);  // [4096][1024] bf16
    short* wgbT           = (short*)(ws + 159924224);           // [16][64][64] bf16

    float* kp_out = (float*)d_out;                 // [32][2048][64]
    float* kv_out = kp_out + 4194304;              // [32][2048][64][64]
    float* out_o  = kv_out + 268435456;            // [4096][1024]
    unsigned short* vh16 = (unsigned short*)(qhkv + 2 * 4194304);

    k_pre<<<dim3(13328), 256, 0, stream>>>(q_in, k_in, v_in, wq_b, wk_b, wv_b,
                                           wq_w, wk_w, wv_w, wc_w, wg,
                                           Xb, biasb, WT, wcT, wgbT);
    gemm_bt<<<dim3(8, 32, 3), 256, 0, stream>>>(Xb, WT, biasb, qhkv, wgbT, qprime, kprime,
                                                4194304L, 1048576L, 1024L, 4194304L, 1);
    k_chunksum<<<dim3(NCH, BH), 64, 0, stream>>>(kprime, vh16, cs);
    k_scan<<<dim3(520), 256, 0, stream>>>(cs);
    k_scanfinal<<<dim3(NCH, BH), 64, 0, stream>>>(kprime, qprime, vh16, cs,
                                                  kp_out, kv_out, attnb);
    gemm_out<<<dim3(8, 64), 256, 0, stream>>>(attnb, wcT, wc_b, out_o);
}